// Round 9
// baseline (244.649 us; speedup 1.0000x reference)
//
#include <hip/hip_runtime.h>
#include <hip/hip_bf16.h>
#include <math.h>

// B=32, T=1024, C=256, HS=64. fp32 in/out, bf16 MFMA internally.
// SINGLE fused kernel (R9): phase1 = projection GEMM, device-scope atomic
// grid barrier (grid 1024 = exactly 4 blocks/CU x 256 CU with LDS 34.8 KB and
// VGPR<=128 => all blocks co-resident => spin barrier is deadlock-free),
// phase2 = flash attention. Barrier fences (__threadfence release/acquire)
// give cross-XCD visibility of fqk/vt2 (per-XCD L2 writeback + invalidate).
// phase1: x tile staged via async global_load_lds (16B/lane); W read fp32
//         direct + in-reg bf16 cvt (192 KB, L2-hot; q rows fold 0.125*log2e).
//         Outputs frag-major: FQK [mblk][cp(16)][r(16)][8] (k|q),
//         VT2 [b][ht(4)][sc(32)][r(16)][8] (V^T A-frags).
// phase2: 4 waves/block, 32-query tile, s-tiles strided across waves (no-max
//         base-2 flash: combine is a pure sum of o/l partials). XCD swizzle
//         pins each batch's K/V to one XCD L2. P^T via per-wave LDS.

#define B_  32
#define T_  1024
#define C_  256
#define HS_ 64
#define QSCALE 0.1803368801111204f   // 0.125 * log2(e)
#define NBLK 1024

typedef __attribute__((ext_vector_type(8))) short bf16x8;
typedef __attribute__((ext_vector_type(4))) float f32x4;

static __device__ __forceinline__ unsigned short f2bf(float f) {
    unsigned u = __builtin_bit_cast(unsigned, f);
    u += 0x7FFFu + ((u >> 16) & 1u);               // RNE
    return (unsigned short)(u >> 16);
}
static __device__ __forceinline__ unsigned pack_bf2(float a, float b) {
    unsigned ua = __builtin_bit_cast(unsigned, a) + 0x8000u;
    unsigned ub = __builtin_bit_cast(unsigned, b) + 0x8000u;
    return __builtin_amdgcn_perm(ub, ua, 0x07060302u);  // [ua.hi16, ub.hi16]
}
static __device__ __forceinline__ bf16x8 cvt8r(float4 v0, float4 v1) {
    union { bf16x8 v; unsigned u[4]; } t;
    t.u[0] = pack_bf2(v0.x, v0.y); t.u[1] = pack_bf2(v0.z, v0.w);
    t.u[2] = pack_bf2(v1.x, v1.y); t.u[3] = pack_bf2(v1.z, v1.w);
    return t.v;
}
static __device__ __forceinline__ bf16x8 cvt8rs(float4 v0, float4 v1, float sc) {
    union { bf16x8 v; unsigned u[4]; } t;
    t.u[0] = pack_bf2(v0.x * sc, v0.y * sc); t.u[1] = pack_bf2(v0.z * sc, v0.w * sc);
    t.u[2] = pack_bf2(v1.x * sc, v1.y * sc); t.u[3] = pack_bf2(v1.z * sc, v1.w * sc);
    return t.v;
}
static __device__ __forceinline__ float fexp2(float x) {
#if __has_builtin(__builtin_amdgcn_exp2f)
    return __builtin_amdgcn_exp2f(x);
#else
    return exp2f(x);
#endif
}
// async global -> LDS, 16 B per lane (lane i lands at l + 16*i)
static __device__ __forceinline__ void gl_lds16(const float* g, void* l) {
    __builtin_amdgcn_global_load_lds(
        (const __attribute__((address_space(1))) unsigned*)g,
        (__attribute__((address_space(3))) unsigned*)l, 16, 0, 0);
}

#define XPITCH 1040   // bytes per x row in LDS (1024 + 16 pad)

__global__ __launch_bounds__(256, 4) void fused_kernel(
    const float* __restrict__ x,
    const float* __restrict__ Wk, const float* __restrict__ Wq,
    const float* __restrict__ Wv,
    unsigned short* __restrict__ fqk, unsigned short* __restrict__ vt2,
    unsigned* __restrict__ cnt, float* __restrict__ out)
{
    __shared__ __align__(16) char smem[34816];   // phase1 xls(33280) U phase2 attn

    const int tid = threadIdx.x;
    const int lane = tid & 63, w = tid >> 6;
    const int q4 = lane >> 4, l15 = lane & 15;

    // ================= phase 1: projection =================
    {
        char* xls = smem;
        const int m0 = blockIdx.x * 32;

        // DMA x rows: wave w stages rows 8w..8w+7 (1 KB per call)
        {
            const float* gbase = &x[(size_t)(m0 + 8 * w) * C_ + lane * 4];
            #pragma unroll
            for (int j = 0; j < 8; ++j)
                gl_lds16(gbase + (size_t)j * C_, xls + (8 * w + j) * XPITCH);
        }

        // W source rows (fp32) per n-tile, lane row = l15, col base q4*8
        const float* wp[3];
        float wsc[3];
        #pragma unroll
        for (int nt = 0; nt < 3; ++nt) {
            const int nb = 48 * w + nt * 16;
            if (nb < 64)       { wp[nt] = &Wk[(size_t)(nb       + l15) * C_ + q4 * 8]; wsc[nt] = 1.0f; }
            else if (nb < 128) { wp[nt] = &Wq[(size_t)(nb - 64  + l15) * C_ + q4 * 8]; wsc[nt] = QSCALE; }
            else               { wp[nt] = &Wv[(size_t)(nb - 128 + l15) * C_ + q4 * 8]; wsc[nt] = 1.0f; }
        }

        f32x4 acc[3][2];
        #pragma unroll
        for (int nt = 0; nt < 3; ++nt)
            #pragma unroll
            for (int mt = 0; mt < 2; ++mt) acc[nt][mt] = (f32x4)0.0f;

        float4 aw[6];
        #pragma unroll
        for (int nt = 0; nt < 3; ++nt) {
            aw[2 * nt]     = *(const float4*)(wp[nt]);
            aw[2 * nt + 1] = *(const float4*)(wp[nt] + 4);
        }

        __syncthreads();   // DMA (and aw loads) complete

        #pragma unroll
        for (int ks = 0; ks < 8; ++ks) {
            bf16x8 bx[2];
            #pragma unroll
            for (int mt = 0; mt < 2; ++mt) {
                const float* p = (const float*)(xls + (mt * 16 + l15) * XPITCH
                                                + (ks * 32 + q4 * 8) * 4);
                float4 v0 = *(const float4*)p;
                float4 v1 = *(const float4*)(p + 4);
                bx[mt] = cvt8r(v0, v1);
            }
            float4 awn[6];
            if (ks < 7) {
                #pragma unroll
                for (int nt = 0; nt < 3; ++nt) {
                    awn[2 * nt]     = *(const float4*)(wp[nt] + (ks + 1) * 32);
                    awn[2 * nt + 1] = *(const float4*)(wp[nt] + (ks + 1) * 32 + 4);
                }
            }
            #pragma unroll
            for (int nt = 0; nt < 3; ++nt) {
                bf16x8 a = cvt8rs(aw[2 * nt], aw[2 * nt + 1], wsc[nt]);
                acc[nt][0] = __builtin_amdgcn_mfma_f32_16x16x32_bf16(a, bx[0], acc[nt][0], 0, 0, 0);
                acc[nt][1] = __builtin_amdgcn_mfma_f32_16x16x32_bf16(a, bx[1], acc[nt][1], 0, 0, 0);
            }
            #pragma unroll
            for (int j = 0; j < 6; ++j) aw[j] = awn[j];
        }

        // epilogue: FQK chunk-pair (coalesced) | VT2 frag-major (32B-run scalars)
        const int mbg = m0 >> 4;
        #pragma unroll
        for (int nt = 0; nt < 3; ++nt) {
            const int c = 48 * w + 16 * nt + 4 * q4;
            #pragma unroll
            for (int mt = 0; mt < 2; ++mt) {
                const int m = m0 + mt * 16 + l15;
                f32x4 v = acc[nt][mt];
                if (c < 128) {       // k | q -> FQK[mb][cp][r][8]
                    uint2 o = make_uint2(pack_bf2(v.x, v.y), pack_bf2(v.z, v.w));
                    *(uint2*)&fqk[(size_t)(mbg + mt) * 2048 + (c >> 3) * 128 + l15 * 8 + (c & 7)] = o;
                } else {             // v -> VT2[b][ht][sc][r(16)][8]
                    const int batch = m >> 10, s = m & 1023;
                    const int hb = c - 128;
                    const int ht = hb >> 4, rb = hb & 15;
                    const int sc = s >> 5, kk = s & 31;
                    unsigned short* dst = &vt2[((((size_t)batch * 4 + ht) * 32 + sc) * 16) * 32
                                               + rb * 32 + kk];
                    dst[0 * 32] = f2bf(v.x);
                    dst[1 * 32] = f2bf(v.y);
                    dst[2 * 32] = f2bf(v.z);
                    dst[3 * 32] = f2bf(v.w);
                }
            }
        }
    }

    // ================= grid barrier (all 1024 blocks co-resident) ============
    __syncthreads();
    if (tid == 0) {
        __threadfence();                              // release: L2 writeback
        atomicAdd(cnt, 1u);
        while (__hip_atomic_load(cnt, __ATOMIC_RELAXED, __HIP_MEMORY_SCOPE_AGENT)
               < (unsigned)NBLK)
            __builtin_amdgcn_s_sleep(2);
        __threadfence();                              // acquire: L2 invalidate
    }
    __syncthreads();

    // ================= phase 2: attention =================
    {
        const int slot  = blockIdx.x >> 3;            // 0..127
        const int batch = (blockIdx.x & 7) * 4 + (slot & 3);
        const int qt    = 31 - (slot >> 2);           // heavy-first per XCD
        const int q0    = qt * 32;
        const int ns    = (qt >> 1) + 1;

        unsigned short (*Ps)[72] = (unsigned short(*)[72])(smem + w * 4608);

        const unsigned short* kb2 = &fqk[(size_t)batch * 64 * 2048];
        const unsigned short* vb2 = &vt2[(size_t)batch * 4 * 32 * 512];

        bf16x8 qf[2][2];
        #pragma unroll
        for (int it = 0; it < 2; ++it)
            #pragma unroll
            for (int kc = 0; kc < 2; ++kc)
                qf[it][kc] = *(const bf16x8*)&kb2[(size_t)((q0 >> 4) + it) * 2048
                                                  + (8 + 4 * kc + q4) * 128 + l15 * 8];

        f32x4 o[4][2];
        #pragma unroll
        for (int ht = 0; ht < 4; ++ht)
            #pragma unroll
            for (int it = 0; it < 2; ++it) o[ht][it] = (f32x4)0.0f;
        float l[2] = {0.f, 0.f};

        for (int st = w; st < ns; st += 4) {
            const int s0 = st * 64;
            const bool last = (st == ns - 1);
            #pragma unroll
            for (int hf = 0; hf < 2; ++hf) {
                const int sh = s0 + hf * 32;
                bf16x8 ak[2][2];
                #pragma unroll
                for (int st16 = 0; st16 < 2; ++st16)
                    #pragma unroll
                    for (int kc = 0; kc < 2; ++kc)
                        ak[st16][kc] = *(const bf16x8*)&kb2[(size_t)((sh >> 4) + st16) * 2048
                                                            + (4 * kc + q4) * 128 + l15 * 8];
                bf16x8 av[4];
                #pragma unroll
                for (int ht = 0; ht < 4; ++ht)
                    av[ht] = *(const bf16x8*)&vb2[((size_t)ht * 32 + (sh >> 5)) * 512
                                                   + l15 * 32 + q4 * 8];
                f32x4 s[2][2];
                #pragma unroll
                for (int st16 = 0; st16 < 2; ++st16)
                    #pragma unroll
                    for (int it = 0; it < 2; ++it) {
                        f32x4 c = (f32x4)0.0f;
                        c = __builtin_amdgcn_mfma_f32_16x16x32_bf16(ak[st16][0], qf[it][0], c, 0, 0, 0);
                        c = __builtin_amdgcn_mfma_f32_16x16x32_bf16(ak[st16][1], qf[it][1], c, 0, 0, 0);
                        s[st16][it] = c;
                    }
                #pragma unroll
                for (int st16 = 0; st16 < 2; ++st16)
                    #pragma unroll
                    for (int it = 0; it < 2; ++it) {
                        const int iloc = it * 16 + l15;
                        float p[4];
                        #pragma unroll
                        for (int r = 0; r < 4; ++r) {
                            float pv = fexp2(s[st16][it][r]);
                            if (last) {
                                int sl = sh + st16 * 16 + q4 * 4 + r;
                                if (sl > q0 + iloc) pv = 0.0f;   // causal
                            }
                            p[r] = pv;
                            l[it] += pv;
                        }
                        uint2 pw = make_uint2(pack_bf2(p[0], p[1]), pack_bf2(p[2], p[3]));
                        *(uint2*)&Ps[iloc][hf * 32 + st16 * 16 + q4 * 4] = pw;
                    }
                #pragma unroll
                for (int it = 0; it < 2; ++it) {
                    bf16x8 bp = *(const bf16x8*)&Ps[it * 16 + l15][hf * 32 + q4 * 8];
                    #pragma unroll
                    for (int ht = 0; ht < 4; ++ht)
                        o[ht][it] = __builtin_amdgcn_mfma_f32_16x16x32_bf16(av[ht], bp, o[ht][it], 0, 0, 0);
                }
            }
        }

        #pragma unroll
        for (int it = 0; it < 2; ++it) {
            l[it] += __shfl_xor(l[it], 16);
            l[it] += __shfl_xor(l[it], 32);
        }

        __syncthreads();   // all waves done with Ps before combine-buffer reuse
        float4* ocomb = (float4*)smem;                 // [w][ht][it][lane]
        float*  lcomb = (float*)(smem + 32768);        // [w][it][lane]
        #pragma unroll
        for (int ht = 0; ht < 4; ++ht)
            #pragma unroll
            for (int it = 0; it < 2; ++it) {
                f32x4 v = o[ht][it];
                ocomb[((w * 4 + ht) * 2 + it) * 64 + lane] = make_float4(v.x, v.y, v.z, v.w);
            }
        #pragma unroll
        for (int it = 0; it < 2; ++it) lcomb[(w * 2 + it) * 64 + lane] = l[it];
        __syncthreads();

        #pragma unroll
        for (int it = 0; it < 2; ++it) {
            float4 a = make_float4(0.f, 0.f, 0.f, 0.f);
            float lt = 0.f;
            #pragma unroll
            for (int src = 0; src < 4; ++src) {
                float4 t = ocomb[((src * 4 + w) * 2 + it) * 64 + lane];
                a.x += t.x; a.y += t.y; a.z += t.z; a.w += t.w;
                lt += lcomb[(src * 2 + it) * 64 + lane];
            }
            float inv = 1.0f / lt;
            float4 res = make_float4(a.x * inv, a.y * inv, a.z * inv, a.w * inv);
            *(float4*)&out[(size_t)(batch * T_ + q0 + it * 16 + l15) * HS_ + w * 16 + q4 * 4] = res;
        }
    }
}

extern "C" void kernel_launch(void* const* d_in, const int* in_sizes, int n_in,
                              void* d_out, int out_size, void* d_ws, size_t ws_size,
                              hipStream_t stream) {
    (void)in_sizes; (void)n_in; (void)out_size; (void)ws_size;
    const float* x  = (const float*)d_in[0];
    const float* Wk = (const float*)d_in[1];
    const float* Wq = (const float*)d_in[2];
    const float* Wv = (const float*)d_in[3];

    unsigned short* fqk = (unsigned short*)d_ws;                                  // 8 MB
    unsigned short* vt2 = (unsigned short*)((char*)d_ws + (size_t)32768 * 128 * 2); // 4 MB
    unsigned* cnt = (unsigned*)((char*)d_ws + (16u << 20));                       // @16 MiB

    hipMemsetAsync(cnt, 0, 128, stream);
    hipLaunchKernelGGL(fused_kernel, dim3(NBLK), dim3(256), 0, stream,
                       x, Wk, Wq, Wv, fqk, vt2, cnt, (float*)d_out);
}

// Round 10
// 132.643 us; speedup vs baseline: 1.8444x; 1.8444x over previous
//
#include <hip/hip_runtime.h>
#include <hip/hip_bf16.h>
#include <math.h>

// R10 = R8 EXACTLY, but attn_kernel launched 3x (idempotent) as a timing
// probe: t_attn = (dur_R10 - dur_R8) / 2. R9 post-mortem: fused kernel hit
// the VGPR=60 load-serialization pathology in both phases + spills (181 us);
// fusion abandoned.
// prep: W -> bf16 wbf[192][256] (k | q*0.125*log2e | v rows).
// proj: x tile via async global_load_lds; W A-frags bf16 from L2-hot wbf.
//       FQK [mblk][cp(16)][r(16)][8] (k|q), VT2 [b][ht(4)][sc(32)][r(16)][8].
// attn: 4 waves/block, 32-q tile, s-tiles strided across waves, no-max
//       base-2 flash, XCD swizzle, P^T via per-wave LDS.

#define B_  32
#define T_  1024
#define C_  256
#define HS_ 64
#define QSCALE 0.1803368801111204f   // 0.125 * log2(e)

typedef __attribute__((ext_vector_type(8))) short bf16x8;
typedef __attribute__((ext_vector_type(4))) float f32x4;

static __device__ __forceinline__ unsigned short f2bf(float f) {
    unsigned u = __builtin_bit_cast(unsigned, f);
    u += 0x7FFFu + ((u >> 16) & 1u);               // RNE
    return (unsigned short)(u >> 16);
}
static __device__ __forceinline__ unsigned pack_bf2(float a, float b) {
    unsigned ua = __builtin_bit_cast(unsigned, a) + 0x8000u;
    unsigned ub = __builtin_bit_cast(unsigned, b) + 0x8000u;
    return __builtin_amdgcn_perm(ub, ua, 0x07060302u);  // [ua.hi16, ub.hi16]
}
static __device__ __forceinline__ bf16x8 cvt8r(float4 v0, float4 v1) {
    union { bf16x8 v; unsigned u[4]; } t;
    t.u[0] = pack_bf2(v0.x, v0.y); t.u[1] = pack_bf2(v0.z, v0.w);
    t.u[2] = pack_bf2(v1.x, v1.y); t.u[3] = pack_bf2(v1.z, v1.w);
    return t.v;
}
static __device__ __forceinline__ float fexp2(float x) {
#if __has_builtin(__builtin_amdgcn_exp2f)
    return __builtin_amdgcn_exp2f(x);
#else
    return exp2f(x);
#endif
}
// async global -> LDS, 16 B per lane (lane i lands at l + 16*i)
static __device__ __forceinline__ void gl_lds16(const float* g, void* l) {
    __builtin_amdgcn_global_load_lds(
        (const __attribute__((address_space(1))) unsigned*)g,
        (__attribute__((address_space(3))) unsigned*)l, 16, 0, 0);
}

// ---------------- prep: W -> bf16 (q rows pre-scaled) ----------------
__global__ __launch_bounds__(256) void prep_kernel(
    const float* __restrict__ Wk, const float* __restrict__ Wq,
    const float* __restrict__ Wv, unsigned short* __restrict__ wbf)
{
    const int idx = blockIdx.x * 256 + threadIdx.x;   // 0..12287 float4s
    const int row = idx >> 6, c4 = (idx & 63) << 2;
    const float* src; float sc = 1.0f;
    if (row < 64)       src = &Wk[(size_t)row * C_];
    else if (row < 128) { src = &Wq[(size_t)(row - 64) * C_]; sc = QSCALE; }
    else                src = &Wv[(size_t)(row - 128) * C_];
    float4 v = *(const float4*)&src[c4];
    uint2 o = make_uint2(pack_bf2(v.x * sc, v.y * sc), pack_bf2(v.z * sc, v.w * sc));
    *(uint2*)&wbf[(size_t)row * C_ + c4] = o;
}

// ---------------- proj: async-staged bf16 MFMA GEMM ----------------
#define XPITCH 1040   // bytes per x row in LDS (1024 + 16 pad)
__global__ __launch_bounds__(256) void proj_kernel(
    const float* __restrict__ x, const unsigned short* __restrict__ wbf,
    unsigned short* __restrict__ fqk, unsigned short* __restrict__ vt2)
{
    __shared__ __align__(16) char xls[32 * XPITCH];   // 33280 B -> 4 blocks/CU

    const int tid = threadIdx.x;
    const int lane = tid & 63, w = tid >> 6;
    const int q4 = lane >> 4, l15 = lane & 15;
    const int m0 = blockIdx.x * 32;

    // stage: wave w DMAs rows 8w..8w+7 (1 KB per call, contiguous per row)
    {
        const float* gbase = &x[(size_t)(m0 + 8 * w) * C_ + lane * 4];
        #pragma unroll
        for (int j = 0; j < 8; ++j)
            gl_lds16(gbase + (size_t)j * C_, xls + (8 * w + j) * XPITCH);
    }

    const unsigned short* wrow = &wbf[(size_t)(48 * w + l15) * C_ + q4 * 8];

    f32x4 acc[3][2];
    #pragma unroll
    for (int nt = 0; nt < 3; ++nt)
        #pragma unroll
        for (int mt = 0; mt < 2; ++mt) acc[nt][mt] = (f32x4)0.0f;

    bf16x8 aw[3];
    #pragma unroll
    for (int nt = 0; nt < 3; ++nt)
        aw[nt] = *(const bf16x8*)&wrow[(size_t)nt * 16 * C_];

    __syncthreads();   // DMA complete (barrier drains vmcnt)

    #pragma unroll
    for (int ks = 0; ks < 8; ++ks) {
        bf16x8 bx[2];
        #pragma unroll
        for (int mt = 0; mt < 2; ++mt) {
            const float* p = (const float*)(xls + (mt * 16 + l15) * XPITCH
                                            + (ks * 32 + q4 * 8) * 4);
            float4 v0 = *(const float4*)p;
            float4 v1 = *(const float4*)(p + 4);
            bx[mt] = cvt8r(v0, v1);
        }
        bf16x8 awn[3];
        if (ks < 7) {
            #pragma unroll
            for (int nt = 0; nt < 3; ++nt)
                awn[nt] = *(const bf16x8*)&wrow[(size_t)nt * 16 * C_ + (ks + 1) * 32];
        }
        #pragma unroll
        for (int nt = 0; nt < 3; ++nt) {
            acc[nt][0] = __builtin_amdgcn_mfma_f32_16x16x32_bf16(aw[nt], bx[0], acc[nt][0], 0, 0, 0);
            acc[nt][1] = __builtin_amdgcn_mfma_f32_16x16x32_bf16(aw[nt], bx[1], acc[nt][1], 0, 0, 0);
        }
        #pragma unroll
        for (int nt = 0; nt < 3; ++nt) aw[nt] = awn[nt];
    }

    const int mbg = m0 >> 4;
    #pragma unroll
    for (int nt = 0; nt < 3; ++nt) {
        const int c = 48 * w + 16 * nt + 4 * q4;
        #pragma unroll
        for (int mt = 0; mt < 2; ++mt) {
            const int m = m0 + mt * 16 + l15;
            f32x4 v = acc[nt][mt];
            if (c < 128) {           // k | q -> FQK[mb][cp][r][8]
                uint2 o = make_uint2(pack_bf2(v.x, v.y), pack_bf2(v.z, v.w));
                *(uint2*)&fqk[(size_t)(mbg + mt) * 2048 + (c >> 3) * 128 + l15 * 8 + (c & 7)] = o;
            } else {                 // v -> VT2[b][ht][sc][r(16)][8]
                const int batch = m >> 10, s = m & 1023;
                const int hb = c - 128;
                const int ht = hb >> 4, rb = hb & 15;
                const int sc = s >> 5, kk = s & 31;
                unsigned short* dst = &vt2[((((size_t)batch * 4 + ht) * 32 + sc) * 16) * 32
                                           + rb * 32 + kk];
                dst[0 * 32] = f2bf(v.x);
                dst[1 * 32] = f2bf(v.y);
                dst[2 * 32] = f2bf(v.z);
                dst[3 * 32] = f2bf(v.w);
            }
        }
    }
}

// ---------------- attention: 4-wave split-s flash, no-max, base-2 ----------------
__global__ __launch_bounds__(256) void attn_kernel(
    const unsigned short* __restrict__ fqk,
    const unsigned short* __restrict__ vt2,
    float* __restrict__ out)
{
    __shared__ __align__(16) char smem[34816];   // Ps[4][32][72] U ocomb+lcomb

    const int tid = threadIdx.x;
    const int lane = tid & 63, w = tid >> 6;
    const int q4 = lane >> 4, l15 = lane & 15;
    const int slot  = blockIdx.x >> 3;            // 0..127
    const int batch = (blockIdx.x & 7) * 4 + (slot & 3);
    const int qt    = 31 - (slot >> 2);           // heavy-first per XCD
    const int q0    = qt * 32;
    const int ns    = (qt >> 1) + 1;

    unsigned short (*Ps)[72] = (unsigned short(*)[72])(smem + w * 4608);

    const unsigned short* kb2 = &fqk[(size_t)batch * 64 * 2048];
    const unsigned short* vb2 = &vt2[(size_t)batch * 4 * 32 * 512];

    bf16x8 qf[2][2];
    #pragma unroll
    for (int it = 0; it < 2; ++it)
        #pragma unroll
        for (int kc = 0; kc < 2; ++kc)
            qf[it][kc] = *(const bf16x8*)&kb2[(size_t)((q0 >> 4) + it) * 2048
                                              + (8 + 4 * kc + q4) * 128 + l15 * 8];

    f32x4 o[4][2];
    #pragma unroll
    for (int ht = 0; ht < 4; ++ht)
        #pragma unroll
        for (int it = 0; it < 2; ++it) o[ht][it] = (f32x4)0.0f;
    float l[2] = {0.f, 0.f};

    for (int st = w; st < ns; st += 4) {
        const int s0 = st * 64;
        const bool last = (st == ns - 1);
        #pragma unroll
        for (int hf = 0; hf < 2; ++hf) {
            const int sh = s0 + hf * 32;
            bf16x8 ak[2][2];
            #pragma unroll
            for (int st16 = 0; st16 < 2; ++st16)
                #pragma unroll
                for (int kc = 0; kc < 2; ++kc)
                    ak[st16][kc] = *(const bf16x8*)&kb2[(size_t)((sh >> 4) + st16) * 2048
                                                        + (4 * kc + q4) * 128 + l15 * 8];
            bf16x8 av[4];
            #pragma unroll
            for (int ht = 0; ht < 4; ++ht)
                av[ht] = *(const bf16x8*)&vb2[((size_t)ht * 32 + (sh >> 5)) * 512
                                               + l15 * 32 + q4 * 8];
            f32x4 s[2][2];
            #pragma unroll
            for (int st16 = 0; st16 < 2; ++st16)
                #pragma unroll
                for (int it = 0; it < 2; ++it) {
                    f32x4 c = (f32x4)0.0f;
                    c = __builtin_amdgcn_mfma_f32_16x16x32_bf16(ak[st16][0], qf[it][0], c, 0, 0, 0);
                    c = __builtin_amdgcn_mfma_f32_16x16x32_bf16(ak[st16][1], qf[it][1], c, 0, 0, 0);
                    s[st16][it] = c;
                }
            #pragma unroll
            for (int st16 = 0; st16 < 2; ++st16)
                #pragma unroll
                for (int it = 0; it < 2; ++it) {
                    const int iloc = it * 16 + l15;
                    float p[4];
                    #pragma unroll
                    for (int r = 0; r < 4; ++r) {
                        float pv = fexp2(s[st16][it][r]);
                        if (last) {
                            int sl = sh + st16 * 16 + q4 * 4 + r;
                            if (sl > q0 + iloc) pv = 0.0f;   // causal
                        }
                        p[r] = pv;
                        l[it] += pv;
                    }
                    uint2 pw = make_uint2(pack_bf2(p[0], p[1]), pack_bf2(p[2], p[3]));
                    *(uint2*)&Ps[iloc][hf * 32 + st16 * 16 + q4 * 4] = pw;
                }
            #pragma unroll
            for (int it = 0; it < 2; ++it) {
                bf16x8 bp = *(const bf16x8*)&Ps[it * 16 + l15][hf * 32 + q4 * 8];
                #pragma unroll
                for (int ht = 0; ht < 4; ++ht)
                    o[ht][it] = __builtin_amdgcn_mfma_f32_16x16x32_bf16(av[ht], bp, o[ht][it], 0, 0, 0);
            }
        }
    }

    #pragma unroll
    for (int it = 0; it < 2; ++it) {
        l[it] += __shfl_xor(l[it], 16);
        l[it] += __shfl_xor(l[it], 32);
    }

    __syncthreads();
    float4* ocomb = (float4*)smem;                 // [w][ht][it][lane]
    float*  lcomb = (float*)(smem + 32768);        // [w][it][lane]
    #pragma unroll
    for (int ht = 0; ht < 4; ++ht)
        #pragma unroll
        for (int it = 0; it < 2; ++it) {
            f32x4 v = o[ht][it];
            ocomb[((w * 4 + ht) * 2 + it) * 64 + lane] = make_float4(v.x, v.y, v.z, v.w);
        }
    #pragma unroll
    for (int it = 0; it < 2; ++it) lcomb[(w * 2 + it) * 64 + lane] = l[it];
    __syncthreads();

    #pragma unroll
    for (int it = 0; it < 2; ++it) {
        float4 a = make_float4(0.f, 0.f, 0.f, 0.f);
        float lt = 0.f;
        #pragma unroll
        for (int src = 0; src < 4; ++src) {
            float4 t = ocomb[((src * 4 + w) * 2 + it) * 64 + lane];
            a.x += t.x; a.y += t.y; a.z += t.z; a.w += t.w;
            lt += lcomb[(src * 2 + it) * 64 + lane];
        }
        float inv = 1.0f / lt;
        float4 res = make_float4(a.x * inv, a.y * inv, a.z * inv, a.w * inv);
        *(float4*)&out[(size_t)(batch * T_ + q0 + it * 16 + l15) * HS_ + w * 16 + q4 * 4] = res;
    }
}

extern "C" void kernel_launch(void* const* d_in, const int* in_sizes, int n_in,
                              void* d_out, int out_size, void* d_ws, size_t ws_size,
                              hipStream_t stream) {
    (void)in_sizes; (void)n_in; (void)out_size; (void)ws_size;
    const float* x  = (const float*)d_in[0];
    const float* Wk = (const float*)d_in[1];
    const float* Wq = (const float*)d_in[2];
    const float* Wv = (const float*)d_in[3];

    unsigned short* wbf = (unsigned short*)d_ws;                                   // 96 KB
    unsigned short* fqk = (unsigned short*)((char*)d_ws + 98304);                  // 8 MB
    unsigned short* vt2 = (unsigned short*)((char*)d_ws + 98304 + (size_t)32768 * 128 * 2); // 4 MB

    hipLaunchKernelGGL(prep_kernel, dim3(48),   dim3(256), 0, stream, Wk, Wq, Wv, wbf);
    hipLaunchKernelGGL(proj_kernel, dim3(1024), dim3(256), 0, stream, x, wbf, fqk, vt2);
    // attn launched 3x (idempotent) as a timing probe: t_attn = (dur - dur_R8)/2
    hipLaunchKernelGGL(attn_kernel, dim3(1024), dim3(256), 0, stream, fqk, vt2, (float*)d_out);
    hipLaunchKernelGGL(attn_kernel, dim3(1024), dim3(256), 0, stream, fqk, vt2, (float*)d_out);
    hipLaunchKernelGGL(attn_kernel, dim3(1024), dim3(256), 0, stream, fqk, vt2, (float*)d_out);
}

// Round 11
// 115.365 us; speedup vs baseline: 2.1207x; 1.1498x over previous
//
#include <hip/hip_runtime.h>
#include <hip/hip_bf16.h>
#include <math.h>

// B=32, T=1024, C=256, HS=64. fp32 in/out, bf16 MFMA internally.
// R11: proj re-tiled to 16-row blocks, grid 2048 -> 8 blocks/CU, 32 waves/CU
//      (R10 probe: attn = 13 us; proj ~28 by subtraction => proj dominates.
//      Theory: per-block DMA-drain latency exposed once per block-slot; double
//      the co-resident blocks to halve the exposure.)
// prep: W -> bf16 wbf[192][256] (k | q*0.125*log2e | v rows).
// proj: x tile (16 rows) via async global_load_lds; W A-frags bf16 from
//       L2-hot wbf, rotating 1-step prefetch. Outputs frag-major:
//       FQK [mblk][cp(16)][r(16)][8] (k|q), VT2 [b][ht(4)][sc(32)][r(16)][8].
// attn: 4 waves/block, 32-q tile, s-tiles strided across waves, no-max
//       base-2 flash, XCD swizzle, P^T via per-wave LDS. (13 us measured)

#define B_  32
#define T_  1024
#define C_  256
#define HS_ 64
#define QSCALE 0.1803368801111204f   // 0.125 * log2(e)

typedef __attribute__((ext_vector_type(8))) short bf16x8;
typedef __attribute__((ext_vector_type(4))) float f32x4;

static __device__ __forceinline__ unsigned short f2bf(float f) {
    unsigned u = __builtin_bit_cast(unsigned, f);
    u += 0x7FFFu + ((u >> 16) & 1u);               // RNE
    return (unsigned short)(u >> 16);
}
static __device__ __forceinline__ unsigned pack_bf2(float a, float b) {
    unsigned ua = __builtin_bit_cast(unsigned, a) + 0x8000u;
    unsigned ub = __builtin_bit_cast(unsigned, b) + 0x8000u;
    return __builtin_amdgcn_perm(ub, ua, 0x07060302u);  // [ua.hi16, ub.hi16]
}
static __device__ __forceinline__ bf16x8 cvt8r(float4 v0, float4 v1) {
    union { bf16x8 v; unsigned u[4]; } t;
    t.u[0] = pack_bf2(v0.x, v0.y); t.u[1] = pack_bf2(v0.z, v0.w);
    t.u[2] = pack_bf2(v1.x, v1.y); t.u[3] = pack_bf2(v1.z, v1.w);
    return t.v;
}
static __device__ __forceinline__ float fexp2(float x) {
#if __has_builtin(__builtin_amdgcn_exp2f)
    return __builtin_amdgcn_exp2f(x);
#else
    return exp2f(x);
#endif
}
// async global -> LDS, 16 B per lane (lane i lands at l + 16*i)
static __device__ __forceinline__ void gl_lds16(const float* g, void* l) {
    __builtin_amdgcn_global_load_lds(
        (const __attribute__((address_space(1))) unsigned*)g,
        (__attribute__((address_space(3))) unsigned*)l, 16, 0, 0);
}

// ---------------- prep: W -> bf16 (q rows pre-scaled) ----------------
__global__ __launch_bounds__(256) void prep_kernel(
    const float* __restrict__ Wk, const float* __restrict__ Wq,
    const float* __restrict__ Wv, unsigned short* __restrict__ wbf)
{
    const int idx = blockIdx.x * 256 + threadIdx.x;   // 0..12287 float4s
    const int row = idx >> 6, c4 = (idx & 63) << 2;
    const float* src; float sc = 1.0f;
    if (row < 64)       src = &Wk[(size_t)row * C_];
    else if (row < 128) { src = &Wq[(size_t)(row - 64) * C_]; sc = QSCALE; }
    else                src = &Wv[(size_t)(row - 128) * C_];
    float4 v = *(const float4*)&src[c4];
    uint2 o = make_uint2(pack_bf2(v.x * sc, v.y * sc), pack_bf2(v.z * sc, v.w * sc));
    *(uint2*)&wbf[(size_t)row * C_ + c4] = o;
}

// ---------------- proj: async-staged bf16 MFMA GEMM, 16-row blocks ----------------
// grid 2048 (16 m-rows each), block 256 = 4 waves; wave w: n in [48w, 48w+48)
#define XPITCH 1040   // bytes per x row in LDS (1024 + 16 pad)
__global__ __launch_bounds__(256) void proj_kernel(
    const float* __restrict__ x, const unsigned short* __restrict__ wbf,
    unsigned short* __restrict__ fqk, unsigned short* __restrict__ vt2)
{
    __shared__ __align__(16) char xls[16 * XPITCH];   // 16.6 KB -> 8 blocks/CU

    const int tid = threadIdx.x;
    const int lane = tid & 63, w = tid >> 6;
    const int q4 = lane >> 4, l15 = lane & 15;
    const int m0 = blockIdx.x * 16;

    // stage: wave w DMAs rows 4w..4w+3 (1 KB per call, contiguous per row)
    {
        const float* gbase = &x[(size_t)(m0 + 4 * w) * C_ + lane * 4];
        #pragma unroll
        for (int j = 0; j < 4; ++j)
            gl_lds16(gbase + (size_t)j * C_, xls + (4 * w + j) * XPITCH);
    }

    const unsigned short* wrow = &wbf[(size_t)(48 * w + l15) * C_ + q4 * 8];

    f32x4 acc[3];
    #pragma unroll
    for (int nt = 0; nt < 3; ++nt) acc[nt] = (f32x4)0.0f;

    bf16x8 aw[3];
    #pragma unroll
    for (int nt = 0; nt < 3; ++nt)
        aw[nt] = *(const bf16x8*)&wrow[(size_t)nt * 16 * C_];

    __syncthreads();   // DMA complete (barrier drains vmcnt)

    #pragma unroll
    for (int ks = 0; ks < 8; ++ks) {
        // B-frag from LDS (fp32 -> bf16 in-reg), row = l15
        const float* p = (const float*)(xls + l15 * XPITCH + (ks * 32 + q4 * 8) * 4);
        float4 v0 = *(const float4*)p;
        float4 v1 = *(const float4*)(p + 4);
        bf16x8 bx = cvt8r(v0, v1);

        bf16x8 awn[3];
        if (ks < 7) {
            #pragma unroll
            for (int nt = 0; nt < 3; ++nt)
                awn[nt] = *(const bf16x8*)&wrow[(size_t)nt * 16 * C_ + (ks + 1) * 32];
        }
        #pragma unroll
        for (int nt = 0; nt < 3; ++nt)
            acc[nt] = __builtin_amdgcn_mfma_f32_16x16x32_bf16(aw[nt], bx, acc[nt], 0, 0, 0);
        #pragma unroll
        for (int nt = 0; nt < 3; ++nt) aw[nt] = awn[nt];
    }

    // epilogue: FQK chunk-pair (coalesced) | VT2 frag-major (32B-run scalars)
    const int m = m0 + l15;
    #pragma unroll
    for (int nt = 0; nt < 3; ++nt) {
        const int c = 48 * w + 16 * nt + 4 * q4;
        f32x4 v = acc[nt];
        if (c < 128) {           // k | q -> FQK[mb][cp][r][8]
            uint2 o = make_uint2(pack_bf2(v.x, v.y), pack_bf2(v.z, v.w));
            *(uint2*)&fqk[(size_t)blockIdx.x * 2048 + (c >> 3) * 128 + l15 * 8 + (c & 7)] = o;
        } else {                 // v -> VT2[b][ht][sc][r(16)][8]
            const int batch = m >> 10, s = m & 1023;
            const int hb = c - 128;
            const int ht = hb >> 4, rb = hb & 15;
            const int sc = s >> 5, kk = s & 31;
            unsigned short* dst = &vt2[((((size_t)batch * 4 + ht) * 32 + sc) * 16) * 32
                                       + rb * 32 + kk];
            dst[0 * 32] = f2bf(v.x);
            dst[1 * 32] = f2bf(v.y);
            dst[2 * 32] = f2bf(v.z);
            dst[3 * 32] = f2bf(v.w);
        }
    }
}

// ---------------- attention: 4-wave split-s flash, no-max, base-2 ----------------
__global__ __launch_bounds__(256) void attn_kernel(
    const unsigned short* __restrict__ fqk,
    const unsigned short* __restrict__ vt2,
    float* __restrict__ out)
{
    __shared__ __align__(16) char smem[34816];   // Ps[4][32][72] U ocomb+lcomb

    const int tid = threadIdx.x;
    const int lane = tid & 63, w = tid >> 6;
    const int q4 = lane >> 4, l15 = lane & 15;
    const int slot  = blockIdx.x >> 3;            // 0..127
    const int batch = (blockIdx.x & 7) * 4 + (slot & 3);
    const int qt    = 31 - (slot >> 2);           // heavy-first per XCD
    const int q0    = qt * 32;
    const int ns    = (qt >> 1) + 1;

    unsigned short (*Ps)[72] = (unsigned short(*)[72])(smem + w * 4608);

    const unsigned short* kb2 = &fqk[(size_t)batch * 64 * 2048];
    const unsigned short* vb2 = &vt2[(size_t)batch * 4 * 32 * 512];

    bf16x8 qf[2][2];
    #pragma unroll
    for (int it = 0; it < 2; ++it)
        #pragma unroll
        for (int kc = 0; kc < 2; ++kc)
            qf[it][kc] = *(const bf16x8*)&kb2[(size_t)((q0 >> 4) + it) * 2048
                                              + (8 + 4 * kc + q4) * 128 + l15 * 8];

    f32x4 o[4][2];
    #pragma unroll
    for (int ht = 0; ht < 4; ++ht)
        #pragma unroll
        for (int it = 0; it < 2; ++it) o[ht][it] = (f32x4)0.0f;
    float l[2] = {0.f, 0.f};

    for (int st = w; st < ns; st += 4) {
        const int s0 = st * 64;
        const bool last = (st == ns - 1);
        #pragma unroll
        for (int hf = 0; hf < 2; ++hf) {
            const int sh = s0 + hf * 32;
            bf16x8 ak[2][2];
            #pragma unroll
            for (int st16 = 0; st16 < 2; ++st16)
                #pragma unroll
                for (int kc = 0; kc < 2; ++kc)
                    ak[st16][kc] = *(const bf16x8*)&kb2[(size_t)((sh >> 4) + st16) * 2048
                                                        + (4 * kc + q4) * 128 + l15 * 8];
            bf16x8 av[4];
            #pragma unroll
            for (int ht = 0; ht < 4; ++ht)
                av[ht] = *(const bf16x8*)&vb2[((size_t)ht * 32 + (sh >> 5)) * 512
                                               + l15 * 32 + q4 * 8];
            f32x4 s[2][2];
            #pragma unroll
            for (int st16 = 0; st16 < 2; ++st16)
                #pragma unroll
                for (int it = 0; it < 2; ++it) {
                    f32x4 c = (f32x4)0.0f;
                    c = __builtin_amdgcn_mfma_f32_16x16x32_bf16(ak[st16][0], qf[it][0], c, 0, 0, 0);
                    c = __builtin_amdgcn_mfma_f32_16x16x32_bf16(ak[st16][1], qf[it][1], c, 0, 0, 0);
                    s[st16][it] = c;
                }
            #pragma unroll
            for (int st16 = 0; st16 < 2; ++st16)
                #pragma unroll
                for (int it = 0; it < 2; ++it) {
                    const int iloc = it * 16 + l15;
                    float p[4];
                    #pragma unroll
                    for (int r = 0; r < 4; ++r) {
                        float pv = fexp2(s[st16][it][r]);
                        if (last) {
                            int sl = sh + st16 * 16 + q4 * 4 + r;
                            if (sl > q0 + iloc) pv = 0.0f;   // causal
                        }
                        p[r] = pv;
                        l[it] += pv;
                    }
                    uint2 pw = make_uint2(pack_bf2(p[0], p[1]), pack_bf2(p[2], p[3]));
                    *(uint2*)&Ps[iloc][hf * 32 + st16 * 16 + q4 * 4] = pw;
                }
            #pragma unroll
            for (int it = 0; it < 2; ++it) {
                bf16x8 bp = *(const bf16x8*)&Ps[it * 16 + l15][hf * 32 + q4 * 8];
                #pragma unroll
                for (int ht = 0; ht < 4; ++ht)
                    o[ht][it] = __builtin_amdgcn_mfma_f32_16x16x32_bf16(av[ht], bp, o[ht][it], 0, 0, 0);
            }
        }
    }

    #pragma unroll
    for (int it = 0; it < 2; ++it) {
        l[it] += __shfl_xor(l[it], 16);
        l[it] += __shfl_xor(l[it], 32);
    }

    __syncthreads();
    float4* ocomb = (float4*)smem;                 // [w][ht][it][lane]
    float*  lcomb = (float*)(smem + 32768);        // [w][it][lane]
    #pragma unroll
    for (int ht = 0; ht < 4; ++ht)
        #pragma unroll
        for (int it = 0; it < 2; ++it) {
            f32x4 v = o[ht][it];
            ocomb[((w * 4 + ht) * 2 + it) * 64 + lane] = make_float4(v.x, v.y, v.z, v.w);
        }
    #pragma unroll
    for (int it = 0; it < 2; ++it) lcomb[(w * 2 + it) * 64 + lane] = l[it];
    __syncthreads();

    #pragma unroll
    for (int it = 0; it < 2; ++it) {
        float4 a = make_float4(0.f, 0.f, 0.f, 0.f);
        float lt = 0.f;
        #pragma unroll
        for (int src = 0; src < 4; ++src) {
            float4 t = ocomb[((src * 4 + w) * 2 + it) * 64 + lane];
            a.x += t.x; a.y += t.y; a.z += t.z; a.w += t.w;
            lt += lcomb[(src * 2 + it) * 64 + lane];
        }
        float inv = 1.0f / lt;
        float4 res = make_float4(a.x * inv, a.y * inv, a.z * inv, a.w * inv);
        *(float4*)&out[(size_t)(batch * T_ + q0 + it * 16 + l15) * HS_ + w * 16 + q4 * 4] = res;
    }
}

extern "C" void kernel_launch(void* const* d_in, const int* in_sizes, int n_in,
                              void* d_out, int out_size, void* d_ws, size_t ws_size,
                              hipStream_t stream) {
    (void)in_sizes; (void)n_in; (void)out_size; (void)ws_size;
    const float* x  = (const float*)d_in[0];
    const float* Wk = (const float*)d_in[1];
    const float* Wq = (const float*)d_in[2];
    const float* Wv = (const float*)d_in[3];

    unsigned short* wbf = (unsigned short*)d_ws;                                   // 96 KB
    unsigned short* fqk = (unsigned short*)((char*)d_ws + 98304);                  // 8 MB
    unsigned short* vt2 = (unsigned short*)((char*)d_ws + 98304 + (size_t)32768 * 128 * 2); // 4 MB

    hipLaunchKernelGGL(prep_kernel, dim3(48),   dim3(256), 0, stream, Wk, Wq, Wv, wbf);
    hipLaunchKernelGGL(proj_kernel, dim3(2048), dim3(256), 0, stream, x, wbf, fqk, vt2);
    hipLaunchKernelGGL(attn_kernel, dim3(1024), dim3(256), 0, stream, fqk, vt2, (float*)d_out);
}

// Round 12
// 100.684 us; speedup vs baseline: 2.4299x; 1.1458x over previous
//
#include <hip/hip_runtime.h>
#include <hip/hip_bf16.h>
#include <math.h>

// B=32, T=1024, C=256, HS=64. fp32 in/out, bf16 MFMA internally.
// R12 = R8 shape (proj 32-row blocks, grid 1024) with two proj fixes:
//  (1) wbf2 frag-major [rb(12)][ks(8)][lane(64)][8]: A-frag load = one
//      contiguous 1KB segment (R8's row-major wbf made every b128 a
//      16-cacheline gather -> TA serialization; R11's doubling of that
//      traffic cost +8.7us, confirming the model).
//  (2) distance-2 A-frag prefetch ring (covers L2 latency with 2 iters).
// prep: W -> bf16 wbf2 chunks (k | q*0.125*log2e | v), ~96 KB.
// proj: x tile via async global_load_lds (pitch 1040, 4 blocks/CU).
//       Outputs frag-major: FQK [mblk][cp(16)][r(16)][8] (k|q),
//       VT2 [b][ht(4)][sc(32)][r(16)][8] (V^T A-frags).
// attn: unchanged R8: 4 waves/block, 32-q tile, split-s no-max base-2 flash,
//       XCD swizzle, P^T via per-wave LDS. (~11 us measured via R10 probe)

#define B_  32
#define T_  1024
#define C_  256
#define HS_ 64
#define QSCALE 0.1803368801111204f   // 0.125 * log2(e)

typedef __attribute__((ext_vector_type(8))) short bf16x8;
typedef __attribute__((ext_vector_type(4))) float f32x4;

static __device__ __forceinline__ unsigned short f2bf(float f) {
    unsigned u = __builtin_bit_cast(unsigned, f);
    u += 0x7FFFu + ((u >> 16) & 1u);               // RNE
    return (unsigned short)(u >> 16);
}
static __device__ __forceinline__ unsigned pack_bf2(float a, float b) {
    unsigned ua = __builtin_bit_cast(unsigned, a) + 0x8000u;
    unsigned ub = __builtin_bit_cast(unsigned, b) + 0x8000u;
    return __builtin_amdgcn_perm(ub, ua, 0x07060302u);  // lo16=bf(a), hi16=bf(b)
}
static __device__ __forceinline__ bf16x8 cvt8r(float4 v0, float4 v1) {
    union { bf16x8 v; unsigned u[4]; } t;
    t.u[0] = pack_bf2(v0.x, v0.y); t.u[1] = pack_bf2(v0.z, v0.w);
    t.u[2] = pack_bf2(v1.x, v1.y); t.u[3] = pack_bf2(v1.z, v1.w);
    return t.v;
}
static __device__ __forceinline__ float fexp2(float x) {
#if __has_builtin(__builtin_amdgcn_exp2f)
    return __builtin_amdgcn_exp2f(x);
#else
    return exp2f(x);
#endif
}
// async global -> LDS, 16 B per lane (lane i lands at l + 16*i)
static __device__ __forceinline__ void gl_lds16(const float* g, void* l) {
    __builtin_amdgcn_global_load_lds(
        (const __attribute__((address_space(1))) unsigned*)g,
        (__attribute__((address_space(3))) unsigned*)l, 16, 0, 0);
}

// ---------------- prep: W -> bf16 frag-major chunks ----------------
// wbf2 chunk (rb, ks) = rows rb*16..+15, cols ks*32..+31; element (q4,l15,j)
// at ((rb*8+ks)*64 + q4*16 + l15)*8 + j  => wave A-frag load = lane*8 contiguous.
__global__ __launch_bounds__(256) void prep_kernel(
    const float* __restrict__ Wk, const float* __restrict__ Wq,
    const float* __restrict__ Wv, unsigned short* __restrict__ wbf2)
{
    const int idx = blockIdx.x * 256 + threadIdx.x;   // 0..12287 float4s
    const int row = idx >> 6, c4 = (idx & 63) << 2;
    const float* src; float sc = 1.0f;
    if (row < 64)       src = &Wk[(size_t)row * C_];
    else if (row < 128) { src = &Wq[(size_t)(row - 64) * C_]; sc = QSCALE; }
    else                src = &Wv[(size_t)(row - 128) * C_];
    float4 v = *(const float4*)&src[c4];
    uint2 o = make_uint2(pack_bf2(v.x * sc, v.y * sc), pack_bf2(v.z * sc, v.w * sc));
    const int rb = row >> 4, l15 = row & 15;
    const int ks = c4 >> 5, q4 = (c4 >> 3) & 3, j = c4 & 7;
    *(uint2*)&wbf2[(size_t)(((rb * 8 + ks) * 64 + q4 * 16 + l15) * 8 + j)] = o;
}

// ---------------- proj: async-staged bf16 MFMA GEMM ----------------
// grid 1024 (32 m-rows each), block 256 = 4 waves; wave w: n in [48w, 48w+48)
#define XPITCH 1040   // bytes per x row in LDS (1024 + 16 pad)
__global__ __launch_bounds__(256) void proj_kernel(
    const float* __restrict__ x, const unsigned short* __restrict__ wbf2,
    unsigned short* __restrict__ fqk, unsigned short* __restrict__ vt2)
{
    __shared__ __align__(16) char xls[32 * XPITCH];   // 33280 B -> 4 blocks/CU

    const int tid = threadIdx.x;
    const int lane = tid & 63, w = tid >> 6;
    const int q4 = lane >> 4, l15 = lane & 15;
    const int m0 = blockIdx.x * 32;

    // stage: wave w DMAs rows 8w..8w+7 (1 KB per call, contiguous per row)
    {
        const float* gbase = &x[(size_t)(m0 + 8 * w) * C_ + lane * 4];
        #pragma unroll
        for (int j = 0; j < 8; ++j)
            gl_lds16(gbase + (size_t)j * C_, xls + (8 * w + j) * XPITCH);
    }

    // A-frag chunks for this wave: rb = 3w + nt; load = one 1KB segment
    const unsigned short* wchunk = &wbf2[(size_t)(3 * w) * 8 * 512 + lane * 8];

    f32x4 acc[3][2];
    #pragma unroll
    for (int nt = 0; nt < 3; ++nt)
        #pragma unroll
        for (int mt = 0; mt < 2; ++mt) acc[nt][mt] = (f32x4)0.0f;

    // distance-2 prefetch ring (overlaps the DMA for ks=0,1)
    bf16x8 awbuf[2][3];
    #pragma unroll
    for (int p = 0; p < 2; ++p)
        #pragma unroll
        for (int nt = 0; nt < 3; ++nt)
            awbuf[p][nt] = *(const bf16x8*)&wchunk[(size_t)(nt * 8 + p) * 512];

    __syncthreads();   // DMA complete (barrier drains vmcnt)

    #pragma unroll
    for (int ks = 0; ks < 8; ++ks) {
        const int cur = ks & 1;
        // B-frags from LDS (fp32 -> bf16 in-reg)
        bf16x8 bx[2];
        #pragma unroll
        for (int mt = 0; mt < 2; ++mt) {
            const float* p = (const float*)(xls + (mt * 16 + l15) * XPITCH
                                            + (ks * 32 + q4 * 8) * 4);
            float4 v0 = *(const float4*)p;
            float4 v1 = *(const float4*)(p + 4);
            bx[mt] = cvt8r(v0, v1);
        }
        #pragma unroll
        for (int nt = 0; nt < 3; ++nt) {
            acc[nt][0] = __builtin_amdgcn_mfma_f32_16x16x32_bf16(awbuf[cur][nt], bx[0], acc[nt][0], 0, 0, 0);
            acc[nt][1] = __builtin_amdgcn_mfma_f32_16x16x32_bf16(awbuf[cur][nt], bx[1], acc[nt][1], 0, 0, 0);
        }
        if (ks < 6) {
            #pragma unroll
            for (int nt = 0; nt < 3; ++nt)
                awbuf[cur][nt] = *(const bf16x8*)&wchunk[(size_t)(nt * 8 + ks + 2) * 512];
        }
    }

    // epilogue: FQK chunk-pair (coalesced) | VT2 frag-major (32B-run scalars)
    const int mbg = m0 >> 4;
    #pragma unroll
    for (int nt = 0; nt < 3; ++nt) {
        const int c = 48 * w + 16 * nt + 4 * q4;
        #pragma unroll
        for (int mt = 0; mt < 2; ++mt) {
            const int m = m0 + mt * 16 + l15;
            f32x4 v = acc[nt][mt];
            if (c < 128) {           // k | q -> FQK[mb][cp][r][8]
                uint2 o = make_uint2(pack_bf2(v.x, v.y), pack_bf2(v.z, v.w));
                *(uint2*)&fqk[(size_t)(mbg + mt) * 2048 + (c >> 3) * 128 + l15 * 8 + (c & 7)] = o;
            } else {                 // v -> VT2[b][ht][sc][r(16)][8]
                const int batch = m >> 10, s = m & 1023;
                const int hb = c - 128;
                const int ht = hb >> 4, rb = hb & 15;
                const int sc = s >> 5, kk = s & 31;
                unsigned short* dst = &vt2[((((size_t)batch * 4 + ht) * 32 + sc) * 16) * 32
                                           + rb * 32 + kk];
                dst[0 * 32] = f2bf(v.x);
                dst[1 * 32] = f2bf(v.y);
                dst[2 * 32] = f2bf(v.z);
                dst[3 * 32] = f2bf(v.w);
            }
        }
    }
}

// ---------------- attention: 4-wave split-s flash, no-max, base-2 ----------------
__global__ __launch_bounds__(256) void attn_kernel(
    const unsigned short* __restrict__ fqk,
    const unsigned short* __restrict__ vt2,
    float* __restrict__ out)
{
    __shared__ __align__(16) char smem[34816];   // Ps[4][32][72] U ocomb+lcomb

    const int tid = threadIdx.x;
    const int lane = tid & 63, w = tid >> 6;
    const int q4 = lane >> 4, l15 = lane & 15;
    const int slot  = blockIdx.x >> 3;            // 0..127
    const int batch = (blockIdx.x & 7) * 4 + (slot & 3);
    const int qt    = 31 - (slot >> 2);           // heavy-first per XCD
    const int q0    = qt * 32;
    const int ns    = (qt >> 1) + 1;

    unsigned short (*Ps)[72] = (unsigned short(*)[72])(smem + w * 4608);

    const unsigned short* kb2 = &fqk[(size_t)batch * 64 * 2048];
    const unsigned short* vb2 = &vt2[(size_t)batch * 4 * 32 * 512];

    bf16x8 qf[2][2];
    #pragma unroll
    for (int it = 0; it < 2; ++it)
        #pragma unroll
        for (int kc = 0; kc < 2; ++kc)
            qf[it][kc] = *(const bf16x8*)&kb2[(size_t)((q0 >> 4) + it) * 2048
                                              + (8 + 4 * kc + q4) * 128 + l15 * 8];

    f32x4 o[4][2];
    #pragma unroll
    for (int ht = 0; ht < 4; ++ht)
        #pragma unroll
        for (int it = 0; it < 2; ++it) o[ht][it] = (f32x4)0.0f;
    float l[2] = {0.f, 0.f};

    for (int st = w; st < ns; st += 4) {
        const int s0 = st * 64;
        const bool last = (st == ns - 1);
        #pragma unroll
        for (int hf = 0; hf < 2; ++hf) {
            const int sh = s0 + hf * 32;
            bf16x8 ak[2][2];
            #pragma unroll
            for (int st16 = 0; st16 < 2; ++st16)
                #pragma unroll
                for (int kc = 0; kc < 2; ++kc)
                    ak[st16][kc] = *(const bf16x8*)&kb2[(size_t)((sh >> 4) + st16) * 2048
                                                        + (4 * kc + q4) * 128 + l15 * 8];
            bf16x8 av[4];
            #pragma unroll
            for (int ht = 0; ht < 4; ++ht)
                av[ht] = *(const bf16x8*)&vb2[((size_t)ht * 32 + (sh >> 5)) * 512
                                               + l15 * 32 + q4 * 8];
            f32x4 s[2][2];
            #pragma unroll
            for (int st16 = 0; st16 < 2; ++st16)
                #pragma unroll
                for (int it = 0; it < 2; ++it) {
                    f32x4 c = (f32x4)0.0f;
                    c = __builtin_amdgcn_mfma_f32_16x16x32_bf16(ak[st16][0], qf[it][0], c, 0, 0, 0);
                    c = __builtin_amdgcn_mfma_f32_16x16x32_bf16(ak[st16][1], qf[it][1], c, 0, 0, 0);
                    s[st16][it] = c;
                }
            #pragma unroll
            for (int st16 = 0; st16 < 2; ++st16)
                #pragma unroll
                for (int it = 0; it < 2; ++it) {
                    const int iloc = it * 16 + l15;
                    float p[4];
                    #pragma unroll
                    for (int r = 0; r < 4; ++r) {
                        float pv = fexp2(s[st16][it][r]);
                        if (last) {
                            int sl = sh + st16 * 16 + q4 * 4 + r;
                            if (sl > q0 + iloc) pv = 0.0f;   // causal
                        }
                        p[r] = pv;
                        l[it] += pv;
                    }
                    uint2 pw = make_uint2(pack_bf2(p[0], p[1]), pack_bf2(p[2], p[3]));
                    *(uint2*)&Ps[iloc][hf * 32 + st16 * 16 + q4 * 4] = pw;
                }
            #pragma unroll
            for (int it = 0; it < 2; ++it) {
                bf16x8 bp = *(const bf16x8*)&Ps[it * 16 + l15][hf * 32 + q4 * 8];
                #pragma unroll
                for (int ht = 0; ht < 4; ++ht)
                    o[ht][it] = __builtin_amdgcn_mfma_f32_16x16x32_bf16(av[ht], bp, o[ht][it], 0, 0, 0);
            }
        }
    }

    #pragma unroll
    for (int it = 0; it < 2; ++it) {
        l[it] += __shfl_xor(l[it], 16);
        l[it] += __shfl_xor(l[it], 32);
    }

    __syncthreads();
    float4* ocomb = (float4*)smem;                 // [w][ht][it][lane]
    float*  lcomb = (float*)(smem + 32768);        // [w][it][lane]
    #pragma unroll
    for (int ht = 0; ht < 4; ++ht)
        #pragma unroll
        for (int it = 0; it < 2; ++it) {
            f32x4 v = o[ht][it];
            ocomb[((w * 4 + ht) * 2 + it) * 64 + lane] = make_float4(v.x, v.y, v.z, v.w);
        }
    #pragma unroll
    for (int it = 0; it < 2; ++it) lcomb[(w * 2 + it) * 64 + lane] = l[it];
    __syncthreads();

    #pragma unroll
    for (int it = 0; it < 2; ++it) {
        float4 a = make_float4(0.f, 0.f, 0.f, 0.f);
        float lt = 0.f;
        #pragma unroll
        for (int src = 0; src < 4; ++src) {
            float4 t = ocomb[((src * 4 + w) * 2 + it) * 64 + lane];
            a.x += t.x; a.y += t.y; a.z += t.z; a.w += t.w;
            lt += lcomb[(src * 2 + it) * 64 + lane];
        }
        float inv = 1.0f / lt;
        float4 res = make_float4(a.x * inv, a.y * inv, a.z * inv, a.w * inv);
        *(float4*)&out[(size_t)(batch * T_ + q0 + it * 16 + l15) * HS_ + w * 16 + q4 * 4] = res;
    }
}

extern "C" void kernel_launch(void* const* d_in, const int* in_sizes, int n_in,
                              void* d_out, int out_size, void* d_ws, size_t ws_size,
                              hipStream_t stream) {
    (void)in_sizes; (void)n_in; (void)out_size; (void)ws_size;
    const float* x  = (const float*)d_in[0];
    const float* Wk = (const float*)d_in[1];
    const float* Wq = (const float*)d_in[2];
    const float* Wv = (const float*)d_in[3];

    unsigned short* wbf2 = (unsigned short*)d_ws;                                  // 96 KB
    unsigned short* fqk  = (unsigned short*)((char*)d_ws + 98304);                 // 8 MB
    unsigned short* vt2  = (unsigned short*)((char*)d_ws + 98304 + (size_t)32768 * 128 * 2); // 4 MB

    hipLaunchKernelGGL(prep_kernel, dim3(48),   dim3(256), 0, stream, Wk, Wq, Wv, wbf2);
    hipLaunchKernelGGL(proj_kernel, dim3(1024), dim3(256), 0, stream, x, wbf2, fqk, vt2);
    hipLaunchKernelGGL(attn_kernel, dim3(1024), dim3(256), 0, stream, fqk, vt2, (float*)d_out);
}